// Round 1
// baseline (289.855 us; speedup 1.0000x reference)
//
#include <hip/hip_runtime.h>
#include <hip/hip_bf16.h>

#define HIDDEN 256
#define HEADS 8
#define HEAD_DIM 32
#define NUM_RBF 32
#define K_PTS 4096
#define N_ATOMS 2048
#define B_MOL 32
#define ATOMS_PER_MOL (N_ATOMS / B_MOL)   // 64

// -------------------------------------------------------------------------
// K1: row GEMM + bias: C[r,c] = sum_d A[r,d] * W[d,c] + b[c]
// one row per block, 256 threads (one per output column)
// -------------------------------------------------------------------------
__global__ __launch_bounds__(HIDDEN) void proj_kernel(
    const float* __restrict__ A, const float* __restrict__ W,
    const float* __restrict__ b, float* __restrict__ C) {
    __shared__ float a_lds[HIDDEN];
    const int r = blockIdx.x;
    const int c = threadIdx.x;
    a_lds[c] = A[r * HIDDEN + c];
    __syncthreads();
    float acc = b[c];
#pragma unroll 8
    for (int d = 0; d < HIDDEN; ++d)
        acc += a_lds[d] * W[d * HIDDEN + c];
    C[r * HIDDEN + c] = acc;
}

// -------------------------------------------------------------------------
// K2: attention. One point per block, 64 threads = 64 atom slots of the
// point's molecule. RBF bias computed once per (point, atom) pair.
// -------------------------------------------------------------------------
__global__ __launch_bounds__(64) void attn_kernel(
    const float* __restrict__ q, const float* __restrict__ kmat,
    const float* __restrict__ vmat,
    const float* __restrict__ pos_point, const float* __restrict__ pos_atom,
    const float* __restrict__ W_rbf, const float* __restrict__ b_rbf,
    const float* __restrict__ centers,
    const int* __restrict__ point_batch, const int* __restrict__ atom_batch,
    float* __restrict__ agg) {
    const int j = blockIdx.x;      // point index
    const int t = threadIdx.x;     // atom slot 0..63
    const int m = point_batch[j];
    const int n = m * ATOMS_PER_MOL + t;
    const bool valid = (atom_batch[n] == m);

    __shared__ float q_lds[HIDDEN];
    __shared__ float w_lds[ATOMS_PER_MOL];

    // stage q row (256 floats, 4 per lane)
#pragma unroll
    for (int i = 0; i < 4; ++i)
        q_lds[t + 64 * i] = q[j * HIDDEN + t + 64 * i];

    // pairwise distance
    const float dx = pos_point[j * 3 + 0] - pos_atom[n * 3 + 0];
    const float dy = pos_point[j * 3 + 1] - pos_atom[n * 3 + 1];
    const float dz = pos_point[j * 3 + 2] - pos_atom[n * 3 + 2];
    const float dist = sqrtf(fmaxf(dx * dx + dy * dy + dz * dz, 0.0f));

    // RBF features: exp(-(dist - c_r)^2 / width), width = (8/32)^2 = 0.0625
    float rbf[NUM_RBF];
#pragma unroll
    for (int r = 0; r < NUM_RBF; ++r) {
        const float dd = dist - centers[r];
        rbf[r] = __expf(-16.0f * dd * dd);
    }
    __syncthreads();

    const float scale = 0.17677669529663687f;  // 32^-0.5

    for (int h = 0; h < HEADS; ++h) {
        // distance bias for this head
        float bias = b_rbf[h];
#pragma unroll
        for (int r = 0; r < NUM_RBF; ++r)
            bias += rbf[r] * W_rbf[r * HEADS + h];

        // q . k
        float dot = 0.0f;
        const float* kp = kmat + n * HIDDEN + h * HEAD_DIM;
        const float* qp = q_lds + h * HEAD_DIM;
#pragma unroll
        for (int d = 0; d < HEAD_DIM; ++d)
            dot += qp[d] * kp[d];

        float score = valid ? (dot * scale + bias) : -1e30f;

        // softmax across the 64 lanes (full wave)
        float mx = score;
#pragma unroll
        for (int off = 32; off > 0; off >>= 1)
            mx = fmaxf(mx, __shfl_xor(mx, off));
        const float e = __expf(score - mx);   // masked lanes -> 0
        float s = e;
#pragma unroll
        for (int off = 32; off > 0; off >>= 1)
            s += __shfl_xor(s, off);
        w_lds[t] = e / s;
        __syncthreads();

        // aggregate: lane d (0..31) computes sum_t w[t] * v[n_t, h, d]
        if (t < HEAD_DIM) {
            float acc = 0.0f;
            const float* vp = vmat + (size_t)(m * ATOMS_PER_MOL) * HIDDEN + h * HEAD_DIM + t;
#pragma unroll 4
            for (int a = 0; a < ATOMS_PER_MOL; ++a)
                acc += w_lds[a] * vp[a * HIDDEN];
            agg[j * HIDDEN + h * HEAD_DIM + t] = acc;
        }
        __syncthreads();
    }
}

// -------------------------------------------------------------------------
// K3: out-projection + residual + layernorm. One point per block, 256 thr.
// -------------------------------------------------------------------------
__global__ __launch_bounds__(HIDDEN) void out_ln_kernel(
    const float* __restrict__ agg, const float* __restrict__ Wo,
    const float* __restrict__ bo, const float* __restrict__ h_point,
    const float* __restrict__ gamma, const float* __restrict__ beta,
    float* __restrict__ out) {
    __shared__ float a_lds[HIDDEN];
    __shared__ float red_a[4];
    __shared__ float red_b[4];
    const int j = blockIdx.x;
    const int c = threadIdx.x;
    const int lane = c & 63;
    const int wave = c >> 6;

    a_lds[c] = agg[j * HIDDEN + c];
    __syncthreads();

    float acc = bo[c];
#pragma unroll 8
    for (int d = 0; d < HIDDEN; ++d)
        acc += a_lds[d] * Wo[d * HIDDEN + c];

    const float x = h_point[j * HIDDEN + c] + acc;

    // mean
    float s = x;
#pragma unroll
    for (int off = 32; off > 0; off >>= 1)
        s += __shfl_xor(s, off);
    if (lane == 0) red_a[wave] = s;
    __syncthreads();
    const float mean = (red_a[0] + red_a[1] + red_a[2] + red_a[3]) * (1.0f / HIDDEN);

    // variance
    const float dxv = x - mean;
    float vs = dxv * dxv;
#pragma unroll
    for (int off = 32; off > 0; off >>= 1)
        vs += __shfl_xor(vs, off);
    if (lane == 0) red_b[wave] = vs;
    __syncthreads();
    const float var = (red_b[0] + red_b[1] + red_b[2] + red_b[3]) * (1.0f / HIDDEN);

    out[j * HIDDEN + c] = dxv * rsqrtf(var + 1e-5f) * gamma[c] + beta[c];
}

// -------------------------------------------------------------------------
extern "C" void kernel_launch(void* const* d_in, const int* in_sizes, int n_in,
                              void* d_out, int out_size, void* d_ws, size_t ws_size,
                              hipStream_t stream) {
    const float* h_point   = (const float*)d_in[0];
    const float* h_atom    = (const float*)d_in[1];
    const float* pos_point = (const float*)d_in[2];
    const float* pos_atom  = (const float*)d_in[3];
    const float* Wq        = (const float*)d_in[4];
    const float* bq        = (const float*)d_in[5];
    const float* Wk        = (const float*)d_in[6];
    const float* bk        = (const float*)d_in[7];
    const float* Wv        = (const float*)d_in[8];
    const float* bv        = (const float*)d_in[9];
    const float* Wo        = (const float*)d_in[10];
    const float* bo        = (const float*)d_in[11];
    const float* W_rbf     = (const float*)d_in[12];
    const float* b_rbf     = (const float*)d_in[13];
    const float* centers   = (const float*)d_in[14];
    const float* gamma     = (const float*)d_in[15];
    const float* beta      = (const float*)d_in[16];
    const int*   point_batch = (const int*)d_in[17];
    const int*   atom_batch  = (const int*)d_in[18];
    float* out = (float*)d_out;

    float* q_ws   = (float*)d_ws;                       // 4096*256
    float* k_ws   = q_ws + (size_t)K_PTS * HIDDEN;      // 2048*256
    float* v_ws   = k_ws + (size_t)N_ATOMS * HIDDEN;    // 2048*256
    float* agg_ws = v_ws + (size_t)N_ATOMS * HIDDEN;    // 4096*256

    proj_kernel<<<K_PTS, HIDDEN, 0, stream>>>(h_point, Wq, bq, q_ws);
    proj_kernel<<<N_ATOMS, HIDDEN, 0, stream>>>(h_atom, Wk, bk, k_ws);
    proj_kernel<<<N_ATOMS, HIDDEN, 0, stream>>>(h_atom, Wv, bv, v_ws);

    attn_kernel<<<K_PTS, 64, 0, stream>>>(q_ws, k_ws, v_ws, pos_point, pos_atom,
                                          W_rbf, b_rbf, centers,
                                          point_batch, atom_batch, agg_ws);

    out_ln_kernel<<<K_PTS, HIDDEN, 0, stream>>>(agg_ws, Wo, bo, h_point,
                                                gamma, beta, out);
}

// Round 2
// 227.893 us; speedup vs baseline: 1.2719x; 1.2719x over previous
//
#include <hip/hip_runtime.h>
#include <hip/hip_bf16.h>

#define HIDDEN 256
#define HEADS 8
#define HEAD_DIM 32
#define NUM_RBF 32
#define K_PTS 4096
#define N_ATOMS 2048
#define B_MOL 32
#define ATOMS_PER_MOL (N_ATOMS / B_MOL)   // 64

// -------------------------------------------------------------------------
// K1: row-tiled GEMM + bias. ROWS rows per block, 256 threads (1/column).
// W re-read from L2 once per ROWS rows instead of once per row.
// -------------------------------------------------------------------------
template <int ROWS>
__global__ __launch_bounds__(HIDDEN) void proj_rows_kernel(
    const float* __restrict__ A, const float* __restrict__ W,
    const float* __restrict__ b, float* __restrict__ C) {
    __shared__ float a_lds[ROWS][HIDDEN];
    const int r0 = blockIdx.x * ROWS;
    const int c = threadIdx.x;
#pragma unroll
    for (int r = 0; r < ROWS; ++r)
        a_lds[r][c] = A[(size_t)(r0 + r) * HIDDEN + c];
    __syncthreads();

    const float bc = b[c];
    float acc[ROWS];
#pragma unroll
    for (int r = 0; r < ROWS; ++r) acc[r] = bc;

    for (int d4 = 0; d4 < HIDDEN / 4; ++d4) {
        const float w0 = W[(size_t)(d4 * 4 + 0) * HIDDEN + c];
        const float w1 = W[(size_t)(d4 * 4 + 1) * HIDDEN + c];
        const float w2 = W[(size_t)(d4 * 4 + 2) * HIDDEN + c];
        const float w3 = W[(size_t)(d4 * 4 + 3) * HIDDEN + c];
#pragma unroll
        for (int r = 0; r < ROWS; ++r) {
            const float4 av = *(const float4*)&a_lds[r][d4 * 4];
            acc[r] += av.x * w0 + av.y * w1 + av.z * w2 + av.w * w3;
        }
    }
#pragma unroll
    for (int r = 0; r < ROWS; ++r)
        C[(size_t)(r0 + r) * HIDDEN + c] = acc[r];
}

// -------------------------------------------------------------------------
// K2: fused K+V projection (shares the h_atom staging).
// -------------------------------------------------------------------------
template <int ROWS>
__global__ __launch_bounds__(HIDDEN) void proj_kv_kernel(
    const float* __restrict__ A,
    const float* __restrict__ Wk, const float* __restrict__ bk,
    const float* __restrict__ Wv, const float* __restrict__ bv,
    float* __restrict__ K, float* __restrict__ V) {
    __shared__ float a_lds[ROWS][HIDDEN];
    const int r0 = blockIdx.x * ROWS;
    const int c = threadIdx.x;
#pragma unroll
    for (int r = 0; r < ROWS; ++r)
        a_lds[r][c] = A[(size_t)(r0 + r) * HIDDEN + c];
    __syncthreads();

    float acck[ROWS], accv[ROWS];
    const float bkc = bk[c], bvc = bv[c];
#pragma unroll
    for (int r = 0; r < ROWS; ++r) { acck[r] = bkc; accv[r] = bvc; }

    for (int d4 = 0; d4 < HIDDEN / 4; ++d4) {
        float wk0 = Wk[(size_t)(d4 * 4 + 0) * HIDDEN + c];
        float wk1 = Wk[(size_t)(d4 * 4 + 1) * HIDDEN + c];
        float wk2 = Wk[(size_t)(d4 * 4 + 2) * HIDDEN + c];
        float wk3 = Wk[(size_t)(d4 * 4 + 3) * HIDDEN + c];
        float wv0 = Wv[(size_t)(d4 * 4 + 0) * HIDDEN + c];
        float wv1 = Wv[(size_t)(d4 * 4 + 1) * HIDDEN + c];
        float wv2 = Wv[(size_t)(d4 * 4 + 2) * HIDDEN + c];
        float wv3 = Wv[(size_t)(d4 * 4 + 3) * HIDDEN + c];
#pragma unroll
        for (int r = 0; r < ROWS; ++r) {
            const float4 av = *(const float4*)&a_lds[r][d4 * 4];
            acck[r] += av.x * wk0 + av.y * wk1 + av.z * wk2 + av.w * wk3;
            accv[r] += av.x * wv0 + av.y * wv1 + av.z * wv2 + av.w * wv3;
        }
    }
#pragma unroll
    for (int r = 0; r < ROWS; ++r) {
        K[(size_t)(r0 + r) * HIDDEN + c] = acck[r];
        V[(size_t)(r0 + r) * HIDDEN + c] = accv[r];
    }
}

// -------------------------------------------------------------------------
// K3: attention, one WAVE per (point, head). 4 waves/block, one barrier.
// Softmax is wave-local (shuffles). Aggregation uses all 64 lanes:
// lanes = (atom-half, dim), combined with one shfl_xor(32).
// -------------------------------------------------------------------------
__global__ __launch_bounds__(256) void attn2_kernel(
    const float* __restrict__ q, const float* __restrict__ kmat,
    const float* __restrict__ vmat,
    const float* __restrict__ pos_point, const float* __restrict__ pos_atom,
    const float* __restrict__ W_rbf, const float* __restrict__ b_rbf,
    const float* __restrict__ centers,
    const int* __restrict__ point_batch, const int* __restrict__ atom_batch,
    float* __restrict__ agg) {
    __shared__ float q_lds[HIDDEN];
    __shared__ float wrbf_lds[NUM_RBF * HEADS];
    __shared__ float centers_lds[NUM_RBF];
    __shared__ float brbf_lds[HEADS];

    const int gb = blockIdx.x;            // 0..2*K_PTS-1
    const int j = gb >> 1;                // point
    const int tid = threadIdx.x;
    const int wave = tid >> 6;
    const int lane = tid & 63;
    const int h = (gb & 1) * 4 + wave;    // head for this wave

    // stage q row + RBF constants
    q_lds[tid] = q[(size_t)j * HIDDEN + tid];
    wrbf_lds[tid] = W_rbf[tid];
    if (tid < NUM_RBF) centers_lds[tid] = centers[tid];
    if (tid < HEADS) brbf_lds[tid] = b_rbf[tid];
    __syncthreads();

    const int m = point_batch[j];
    const int n = m * ATOMS_PER_MOL + lane;
    const bool valid = (atom_batch[n] == m);

    // distance for (point j, atom n)
    const float px = pos_point[j * 3 + 0], py = pos_point[j * 3 + 1], pz = pos_point[j * 3 + 2];
    const float dx = px - pos_atom[n * 3 + 0];
    const float dy = py - pos_atom[n * 3 + 1];
    const float dz = pz - pos_atom[n * 3 + 2];
    const float dist = sqrtf(fmaxf(dx * dx + dy * dy + dz * dz, 0.0f));

    // RBF bias for this head (width = (8/32)^2 = 0.0625 -> -1/width = -16)
    float bias = brbf_lds[h];
#pragma unroll
    for (int r = 0; r < NUM_RBF; ++r) {
        const float dd = dist - centers_lds[r];
        bias += __expf(-16.0f * dd * dd) * wrbf_lds[r * HEADS + h];
    }

    // q . k  over this head's 32 dims (vectorized)
    const float4* kp = (const float4*)(kmat + (size_t)n * HIDDEN + h * HEAD_DIM);
    const float4* qp = (const float4*)(q_lds + h * HEAD_DIM);
    float dot = 0.0f;
#pragma unroll
    for (int i = 0; i < HEAD_DIM / 4; ++i) {
        const float4 kv = kp[i];
        const float4 qv = qp[i];
        dot += qv.x * kv.x + qv.y * kv.y + qv.z * kv.z + qv.w * kv.w;
    }

    const float scale = 0.17677669529663687f;  // 32^-0.5
    const float score = valid ? (dot * scale + bias) : -1e30f;

    // wave softmax
    float mx = score;
#pragma unroll
    for (int off = 32; off > 0; off >>= 1)
        mx = fmaxf(mx, __shfl_xor(mx, off));
    const float e = __expf(score - mx);
    float s = e;
#pragma unroll
    for (int off = 32; off > 0; off >>= 1)
        s += __shfl_xor(s, off);
    const float w = e / s;   // lane t holds softmax weight of atom t

    // aggregation: lane = (half, d); each half sums 32 atoms, coalesced loads
    const int half = lane >> 5;
    const int d = lane & 31;
    const float* vbase = vmat + (size_t)(m * ATOMS_PER_MOL) * HIDDEN + h * HEAD_DIM + d;
    float acc = 0.0f;
#pragma unroll 8
    for (int a = 0; a < 32; ++a) {
        const int atom = a + 32 * half;
        const float wv = __shfl(w, atom);
        acc += wv * vbase[(size_t)atom * HIDDEN];
    }
    acc += __shfl_xor(acc, 32);
    if (lane < 32)
        agg[(size_t)j * HIDDEN + h * HEAD_DIM + lane] = acc;
}

// -------------------------------------------------------------------------
// K4: out-projection + residual + layernorm, 16 rows/block.
// -------------------------------------------------------------------------
template <int ROWS>
__global__ __launch_bounds__(HIDDEN) void out_ln_kernel(
    const float* __restrict__ agg, const float* __restrict__ Wo,
    const float* __restrict__ bo, const float* __restrict__ h_point,
    const float* __restrict__ gamma, const float* __restrict__ beta,
    float* __restrict__ out) {
    __shared__ float a_lds[ROWS][HIDDEN];
    __shared__ float red_a[ROWS][4];
    __shared__ float red_b[ROWS][4];
    const int r0 = blockIdx.x * ROWS;
    const int c = threadIdx.x;
    const int lane = c & 63;
    const int wave = c >> 6;

#pragma unroll
    for (int r = 0; r < ROWS; ++r)
        a_lds[r][c] = agg[(size_t)(r0 + r) * HIDDEN + c];
    __syncthreads();

    const float bc = bo[c];
    float x[ROWS];
#pragma unroll
    for (int r = 0; r < ROWS; ++r) x[r] = bc;

    for (int d4 = 0; d4 < HIDDEN / 4; ++d4) {
        const float w0 = Wo[(size_t)(d4 * 4 + 0) * HIDDEN + c];
        const float w1 = Wo[(size_t)(d4 * 4 + 1) * HIDDEN + c];
        const float w2 = Wo[(size_t)(d4 * 4 + 2) * HIDDEN + c];
        const float w3 = Wo[(size_t)(d4 * 4 + 3) * HIDDEN + c];
#pragma unroll
        for (int r = 0; r < ROWS; ++r) {
            const float4 av = *(const float4*)&a_lds[r][d4 * 4];
            x[r] += av.x * w0 + av.y * w1 + av.z * w2 + av.w * w3;
        }
    }

    // residual + per-row reduce (sum, sumsq together)
#pragma unroll
    for (int r = 0; r < ROWS; ++r) {
        x[r] += h_point[(size_t)(r0 + r) * HIDDEN + c];
        float s = x[r], ss = x[r] * x[r];
#pragma unroll
        for (int off = 32; off > 0; off >>= 1) {
            s += __shfl_xor(s, off);
            ss += __shfl_xor(ss, off);
        }
        if (lane == 0) { red_a[r][wave] = s; red_b[r][wave] = ss; }
    }
    __syncthreads();

    const float gc = gamma[c], btc = beta[c];
#pragma unroll
    for (int r = 0; r < ROWS; ++r) {
        const float mean = (red_a[r][0] + red_a[r][1] + red_a[r][2] + red_a[r][3]) * (1.0f / HIDDEN);
        const float ex2  = (red_b[r][0] + red_b[r][1] + red_b[r][2] + red_b[r][3]) * (1.0f / HIDDEN);
        const float var = ex2 - mean * mean;
        out[(size_t)(r0 + r) * HIDDEN + c] = (x[r] - mean) * rsqrtf(var + 1e-5f) * gc + btc;
    }
}

// -------------------------------------------------------------------------
extern "C" void kernel_launch(void* const* d_in, const int* in_sizes, int n_in,
                              void* d_out, int out_size, void* d_ws, size_t ws_size,
                              hipStream_t stream) {
    const float* h_point   = (const float*)d_in[0];
    const float* h_atom    = (const float*)d_in[1];
    const float* pos_point = (const float*)d_in[2];
    const float* pos_atom  = (const float*)d_in[3];
    const float* Wq        = (const float*)d_in[4];
    const float* bq        = (const float*)d_in[5];
    const float* Wk        = (const float*)d_in[6];
    const float* bk        = (const float*)d_in[7];
    const float* Wv        = (const float*)d_in[8];
    const float* bv        = (const float*)d_in[9];
    const float* Wo        = (const float*)d_in[10];
    const float* bo        = (const float*)d_in[11];
    const float* W_rbf     = (const float*)d_in[12];
    const float* b_rbf     = (const float*)d_in[13];
    const float* centers   = (const float*)d_in[14];
    const float* gamma     = (const float*)d_in[15];
    const float* beta      = (const float*)d_in[16];
    const int*   point_batch = (const int*)d_in[17];
    const int*   atom_batch  = (const int*)d_in[18];
    float* out = (float*)d_out;

    float* q_ws   = (float*)d_ws;                       // 4096*256
    float* k_ws   = q_ws + (size_t)K_PTS * HIDDEN;      // 2048*256
    float* v_ws   = k_ws + (size_t)N_ATOMS * HIDDEN;    // 2048*256
    float* agg_ws = v_ws + (size_t)N_ATOMS * HIDDEN;    // 4096*256

    proj_rows_kernel<16><<<K_PTS / 16, HIDDEN, 0, stream>>>(h_point, Wq, bq, q_ws);
    proj_kv_kernel<8><<<N_ATOMS / 8, HIDDEN, 0, stream>>>(h_atom, Wk, bk, Wv, bv, k_ws, v_ws);

    attn2_kernel<<<K_PTS * 2, 256, 0, stream>>>(q_ws, k_ws, v_ws, pos_point, pos_atom,
                                                W_rbf, b_rbf, centers,
                                                point_batch, atom_batch, agg_ws);

    out_ln_kernel<16><<<K_PTS / 16, HIDDEN, 0, stream>>>(agg_ws, Wo, bo, h_point,
                                                         gamma, beta, out);
}

// Round 3
// 173.819 us; speedup vs baseline: 1.6676x; 1.3111x over previous
//
#include <hip/hip_runtime.h>
#include <hip/hip_bf16.h>

#define HIDDEN 256
#define HEADS 8
#define HEAD_DIM 32
#define NUM_RBF 32
#define K_PTS 4096
#define N_ATOMS 2048
#define B_MOL 32
#define ATOMS_PER_MOL (N_ATOMS / B_MOL)   // 64

typedef __attribute__((ext_vector_type(8))) short bf16x8;
typedef __attribute__((ext_vector_type(4))) float f32x4;

// -------------------------------------------------------------------------
// K0: prep — bf16 conversions + weight transposes.
//   hpb = bf16(h_point); hab = bf16(h_atom); W*T[c][d] = bf16(W*[d][c])
// -------------------------------------------------------------------------
__global__ __launch_bounds__(256) void prep_kernel(
    const float* __restrict__ hp, const float* __restrict__ ha,
    const float* __restrict__ Wq, const float* __restrict__ Wk,
    const float* __restrict__ Wv, const float* __restrict__ Wo,
    __hip_bfloat16* __restrict__ hpb, __hip_bfloat16* __restrict__ hab,
    __hip_bfloat16* __restrict__ WqT, __hip_bfloat16* __restrict__ WkT,
    __hip_bfloat16* __restrict__ WvT, __hip_bfloat16* __restrict__ WoT) {
    const int i = blockIdx.x * 256 + threadIdx.x;
    const int NHP = K_PTS * HIDDEN;    // 1048576
    const int NHA = N_ATOMS * HIDDEN;  // 524288
    if (i < NHP) {
        hpb[i] = __float2bfloat16(hp[i]);
        if (i < NHA) hab[i] = __float2bfloat16(ha[i]);
        return;
    }
    const int j = i - NHP;             // 0 .. 4*65536-1
    const int w = j >> 16;             // which weight (uniform per block)
    const int idx = j & 65535;
    const int c = idx >> 8, d = idx & 255;
    const float* Ws = (w == 0) ? Wq : (w == 1) ? Wk : (w == 2) ? Wv : Wo;
    __hip_bfloat16* Wd = (w == 0) ? WqT : (w == 1) ? WkT : (w == 2) ? WvT : WoT;
    Wd[c * HIDDEN + d] = __float2bfloat16(Ws[d * HIDDEN + c]);
}

// -------------------------------------------------------------------------
// K1: MFMA GEMM. C[M][256] = A_bf16[M][256] . W (given as WT[c][k] bf16) + b
// Block: 16 rows x 256 cols, 4 waves; wave = 16x64 (4 frags x 8 k-steps).
// NW=2 computes two outputs sharing the A fragments (K and V).
// -------------------------------------------------------------------------
template <int NW>
__global__ __launch_bounds__(256) void gemm_kernel(
    const __hip_bfloat16* __restrict__ A,
    const __hip_bfloat16* __restrict__ W0T, const float* __restrict__ b0,
    float* __restrict__ C0,
    const __hip_bfloat16* __restrict__ W1T, const float* __restrict__ b1,
    float* __restrict__ C1) {
    const int r0 = blockIdx.x * 16;
    const int wave = threadIdx.x >> 6, lane = threadIdx.x & 63;
    const int c0 = wave * 64;
    const int lrow = lane & 15, kgrp = lane >> 4;

    // A fragments for all 8 k-steps (16B contiguous per lane)
    bf16x8 af[8];
    const short* Arow = (const short*)A + (size_t)(r0 + lrow) * HIDDEN + kgrp * 8;
#pragma unroll
    for (int ks = 0; ks < 8; ++ks)
        af[ks] = *(const bf16x8*)(Arow + ks * 32);

    f32x4 acc[NW][4];
#pragma unroll
    for (int wsel = 0; wsel < NW; ++wsel)
#pragma unroll
        for (int cc = 0; cc < 4; ++cc)
            acc[wsel][cc] = (f32x4){0.f, 0.f, 0.f, 0.f};

#pragma unroll
    for (int cc = 0; cc < 4; ++cc) {
        const short* W0r = (const short*)W0T + (size_t)(c0 + cc * 16 + lrow) * HIDDEN + kgrp * 8;
#pragma unroll
        for (int ks = 0; ks < 8; ++ks)
            acc[0][cc] = __builtin_amdgcn_mfma_f32_16x16x32_bf16(
                af[ks], *(const bf16x8*)(W0r + ks * 32), acc[0][cc], 0, 0, 0);
        if (NW == 2) {
            const short* W1r = (const short*)W1T + (size_t)(c0 + cc * 16 + lrow) * HIDDEN + kgrp * 8;
#pragma unroll
            for (int ks = 0; ks < 8; ++ks)
                acc[1][cc] = __builtin_amdgcn_mfma_f32_16x16x32_bf16(
                    af[ks], *(const bf16x8*)(W1r + ks * 32), acc[1][cc], 0, 0, 0);
        }
    }

    // D layout: col = lane&15, row = (lane>>4)*4 + reg   [m89]
    const int colb = lane & 15;
    const int rowb = (lane >> 4) * 4;
#pragma unroll
    for (int cc = 0; cc < 4; ++cc) {
        const int cgl = c0 + cc * 16 + colb;
        const float bias0 = b0[cgl];
#pragma unroll
        for (int rg = 0; rg < 4; ++rg)
            C0[(size_t)(r0 + rowb + rg) * HIDDEN + cgl] = acc[0][cc][rg] + bias0;
        if (NW == 2) {
            const float bias1 = b1[cgl];
#pragma unroll
            for (int rg = 0; rg < 4; ++rg)
                C1[(size_t)(r0 + rowb + rg) * HIDDEN + cgl] = acc[1][cc][rg] + bias1;
        }
    }
}

// -------------------------------------------------------------------------
// K2: attention, one WAVE per (point, head). PV weights broadcast via LDS
// (no dynamic __shfl -> no ds_bpermute chain). agg written as bf16.
// -------------------------------------------------------------------------
__global__ __launch_bounds__(256) void attn2_kernel(
    const float* __restrict__ q, const float* __restrict__ kmat,
    const float* __restrict__ vmat,
    const float* __restrict__ pos_point, const float* __restrict__ pos_atom,
    const float* __restrict__ W_rbf, const float* __restrict__ b_rbf,
    const float* __restrict__ centers,
    const int* __restrict__ point_batch, const int* __restrict__ atom_batch,
    __hip_bfloat16* __restrict__ aggb) {
    __shared__ float q_lds[HIDDEN];
    __shared__ float wrbf_lds[NUM_RBF * HEADS];
    __shared__ float centers_lds[NUM_RBF];
    __shared__ float brbf_lds[HEADS];
    __shared__ float w_lds[4][ATOMS_PER_MOL];

    const int gb = blockIdx.x;            // 0..2*K_PTS-1
    const int j = gb >> 1;                // point
    const int tid = threadIdx.x;
    const int wave = tid >> 6;
    const int lane = tid & 63;
    const int h = (gb & 1) * 4 + wave;    // head for this wave

    q_lds[tid] = q[(size_t)j * HIDDEN + tid];
    wrbf_lds[tid] = W_rbf[tid];
    if (tid < NUM_RBF) centers_lds[tid] = centers[tid];
    if (tid < HEADS) brbf_lds[tid] = b_rbf[tid];
    __syncthreads();

    const int m = point_batch[j];
    const int n = m * ATOMS_PER_MOL + lane;
    const bool valid = (atom_batch[n] == m);

    const float px = pos_point[j * 3 + 0], py = pos_point[j * 3 + 1], pz = pos_point[j * 3 + 2];
    const float dx = px - pos_atom[n * 3 + 0];
    const float dy = py - pos_atom[n * 3 + 1];
    const float dz = pz - pos_atom[n * 3 + 2];
    const float dist = sqrtf(fmaxf(dx * dx + dy * dy + dz * dz, 0.0f));

    // RBF bias for this head; width = (8/32)^2 -> -1/width = -16
    float bias = brbf_lds[h];
#pragma unroll
    for (int r = 0; r < NUM_RBF; ++r) {
        const float dd = dist - centers_lds[r];
        bias += __expf(-16.0f * dd * dd) * wrbf_lds[r * HEADS + h];
    }

    const float4* kp = (const float4*)(kmat + (size_t)n * HIDDEN + h * HEAD_DIM);
    const float4* qp = (const float4*)(q_lds + h * HEAD_DIM);
    float dot = 0.0f;
#pragma unroll
    for (int i = 0; i < HEAD_DIM / 4; ++i) {
        const float4 kv = kp[i];
        const float4 qv = qp[i];
        dot += qv.x * kv.x + qv.y * kv.y + qv.z * kv.z + qv.w * kv.w;
    }

    const float scale = 0.17677669529663687f;  // 32^-0.5
    const float score = valid ? (dot * scale + bias) : -1e30f;

    // wave softmax (xor patterns compile to dpp/permlane — cheap)
    float mx = score;
#pragma unroll
    for (int off = 32; off > 0; off >>= 1)
        mx = fmaxf(mx, __shfl_xor(mx, off));
    const float e = __expf(score - mx);
    float s = e;
#pragma unroll
    for (int off = 32; off > 0; off >>= 1)
        s += __shfl_xor(s, off);
    w_lds[wave][lane] = e / s;   // per-wave region, same-wave consume

    // aggregation: lane = (half, d); w broadcast via ds_read_b128
    const int half = lane >> 5;
    const int d = lane & 31;
    const float* vbase = vmat + (size_t)(m * ATOMS_PER_MOL) * HIDDEN + h * HEAD_DIM + d;
    const float4* wp = (const float4*)(&w_lds[wave][32 * half]);
    float acc = 0.0f;
#pragma unroll
    for (int a4 = 0; a4 < 8; ++a4) {
        const float4 wv = wp[a4];
        const float* vb = vbase + (size_t)(32 * half + a4 * 4) * HIDDEN;
        acc += wv.x * vb[0] + wv.y * vb[HIDDEN] + wv.z * vb[2 * HIDDEN] + wv.w * vb[3 * HIDDEN];
    }
    acc += __shfl_xor(acc, 32);
    if (lane < 32)
        aggb[(size_t)j * HIDDEN + h * HEAD_DIM + lane] = __float2bfloat16(acc);
}

// -------------------------------------------------------------------------
// K3: out-projection (MFMA) + residual + layernorm fused.
// Block: 16 rows x 256 cols (full rows -> LN in epilogue via LDS).
// -------------------------------------------------------------------------
__global__ __launch_bounds__(256) void gemm_o_ln_kernel(
    const __hip_bfloat16* __restrict__ A,   // agg bf16 [4096][256]
    const __hip_bfloat16* __restrict__ WoT, const float* __restrict__ bo,
    const float* __restrict__ h_point,
    const float* __restrict__ gamma, const float* __restrict__ beta,
    float* __restrict__ out) {
    __shared__ float x_lds[16][HIDDEN + 1];   // +1 pad: spread row-stride banks
    __shared__ float red_s[16][4];
    __shared__ float red_q[16][4];

    const int r0 = blockIdx.x * 16;
    const int wave = threadIdx.x >> 6, lane = threadIdx.x & 63;
    const int c0 = wave * 64;
    const int lrow = lane & 15, kgrp = lane >> 4;

    bf16x8 af[8];
    const short* Arow = (const short*)A + (size_t)(r0 + lrow) * HIDDEN + kgrp * 8;
#pragma unroll
    for (int ks = 0; ks < 8; ++ks)
        af[ks] = *(const bf16x8*)(Arow + ks * 32);

    f32x4 acc[4];
#pragma unroll
    for (int cc = 0; cc < 4; ++cc) acc[cc] = (f32x4){0.f, 0.f, 0.f, 0.f};

#pragma unroll
    for (int cc = 0; cc < 4; ++cc) {
        const short* Wr = (const short*)WoT + (size_t)(c0 + cc * 16 + lrow) * HIDDEN + kgrp * 8;
#pragma unroll
        for (int ks = 0; ks < 8; ++ks)
            acc[cc] = __builtin_amdgcn_mfma_f32_16x16x32_bf16(
                af[ks], *(const bf16x8*)(Wr + ks * 32), acc[cc], 0, 0, 0);
    }

    // x = proj + bias + residual -> LDS
    const int colb = lane & 15;
    const int rowb = (lane >> 4) * 4;
#pragma unroll
    for (int cc = 0; cc < 4; ++cc) {
        const int cgl = c0 + cc * 16 + colb;
        const float bias = bo[cgl];
#pragma unroll
        for (int rg = 0; rg < 4; ++rg) {
            const int rl = rowb + rg;
            x_lds[rl][cgl] = acc[cc][rg] + bias + h_point[(size_t)(r0 + rl) * HIDDEN + cgl];
        }
    }
    __syncthreads();

    // LN: thread c handles column c for all 16 rows
    const int c = threadIdx.x;
    const int ln = c & 63, wv = c >> 6;
    float xv[16];
#pragma unroll
    for (int r = 0; r < 16; ++r) {
        xv[r] = x_lds[r][c];
        float s = xv[r], qq = xv[r] * xv[r];
#pragma unroll
        for (int off = 32; off > 0; off >>= 1) {
            s += __shfl_xor(s, off);
            qq += __shfl_xor(qq, off);
        }
        if (ln == 0) { red_s[r][wv] = s; red_q[r][wv] = qq; }
    }
    __syncthreads();

    const float gc = gamma[c], bc = beta[c];
#pragma unroll
    for (int r = 0; r < 16; ++r) {
        const float mean = (red_s[r][0] + red_s[r][1] + red_s[r][2] + red_s[r][3]) * (1.0f / HIDDEN);
        const float ex2  = (red_q[r][0] + red_q[r][1] + red_q[r][2] + red_q[r][3]) * (1.0f / HIDDEN);
        const float var = ex2 - mean * mean;
        out[(size_t)(r0 + r) * HIDDEN + c] = (xv[r] - mean) * rsqrtf(var + 1e-5f) * gc + bc;
    }
}

// -------------------------------------------------------------------------
extern "C" void kernel_launch(void* const* d_in, const int* in_sizes, int n_in,
                              void* d_out, int out_size, void* d_ws, size_t ws_size,
                              hipStream_t stream) {
    const float* h_point   = (const float*)d_in[0];
    const float* h_atom    = (const float*)d_in[1];
    const float* pos_point = (const float*)d_in[2];
    const float* pos_atom  = (const float*)d_in[3];
    const float* Wq        = (const float*)d_in[4];
    const float* bq        = (const float*)d_in[5];
    const float* Wk        = (const float*)d_in[6];
    const float* bk        = (const float*)d_in[7];
    const float* Wv        = (const float*)d_in[8];
    const float* bv        = (const float*)d_in[9];
    const float* Wo        = (const float*)d_in[10];
    const float* bo        = (const float*)d_in[11];
    const float* W_rbf     = (const float*)d_in[12];
    const float* b_rbf     = (const float*)d_in[13];
    const float* centers   = (const float*)d_in[14];
    const float* gamma     = (const float*)d_in[15];
    const float* beta      = (const float*)d_in[16];
    const int*   point_batch = (const int*)d_in[17];
    const int*   atom_batch  = (const int*)d_in[18];
    float* out = (float*)d_out;

    // workspace layout (float slots)
    float* q_ws = (float*)d_ws;                                   // 1048576 f
    float* k_ws = q_ws + (size_t)K_PTS * HIDDEN;                  //  524288 f
    float* v_ws = k_ws + (size_t)N_ATOMS * HIDDEN;                //  524288 f
    __hip_bfloat16* hp_b = (__hip_bfloat16*)(v_ws + (size_t)N_ATOMS * HIDDEN); // 1048576 bf
    __hip_bfloat16* ha_b = hp_b + (size_t)K_PTS * HIDDEN;         //  524288 bf
    __hip_bfloat16* WqT = ha_b + (size_t)N_ATOMS * HIDDEN;        //   65536 bf each
    __hip_bfloat16* WkT = WqT + HIDDEN * HIDDEN;
    __hip_bfloat16* WvT = WkT + HIDDEN * HIDDEN;
    __hip_bfloat16* WoT = WvT + HIDDEN * HIDDEN;
    __hip_bfloat16* agg_b = hp_b;   // alias: hp_b dead after gemm_q

    const int prep_blocks = (K_PTS * HIDDEN + 4 * HIDDEN * HIDDEN) / 256; // 5120
    prep_kernel<<<prep_blocks, 256, 0, stream>>>(h_point, h_atom, Wq, Wk, Wv, Wo,
                                                 hp_b, ha_b, WqT, WkT, WvT, WoT);

    gemm_kernel<1><<<K_PTS / 16, 256, 0, stream>>>(hp_b, WqT, bq, q_ws,
                                                   nullptr, nullptr, nullptr);
    gemm_kernel<2><<<N_ATOMS / 16, 256, 0, stream>>>(ha_b, WkT, bk, k_ws,
                                                     WvT, bv, v_ws);

    attn2_kernel<<<K_PTS * 2, 256, 0, stream>>>(q_ws, k_ws, v_ws, pos_point, pos_atom,
                                                W_rbf, b_rbf, centers,
                                                point_batch, atom_batch, agg_b);

    gemm_o_ln_kernel<<<K_PTS / 16, 256, 0, stream>>>(agg_b, WoT, bo, h_point,
                                                     gamma, beta, out);
}

// Round 4
// 147.062 us; speedup vs baseline: 1.9710x; 1.1819x over previous
//
#include <hip/hip_runtime.h>
#include <hip/hip_bf16.h>

#define HIDDEN 256
#define HEADS 8
#define HEAD_DIM 32
#define NUM_RBF 32
#define K_PTS 4096
#define N_ATOMS 2048
#define B_MOL 32
#define ATOMS_PER_MOL (N_ATOMS / B_MOL)   // 64

typedef __attribute__((ext_vector_type(8))) short bf16x8;
typedef __attribute__((ext_vector_type(4))) float f32x4;

// -------------------------------------------------------------------------
// K0: prep2 — vectorized bf16 conversions + LDS-tiled weight transposes.
// blocks [0,512): hp convert (x8/thread); [512,768): ha convert;
// blocks [768,1024): 32x32 transpose tiles of Wq/Wk/Wv/Wo -> WT bf16.
// -------------------------------------------------------------------------
__global__ __launch_bounds__(256) void prep2_kernel(
    const float* __restrict__ hp, const float* __restrict__ ha,
    const float* __restrict__ Wq, const float* __restrict__ Wk,
    const float* __restrict__ Wv, const float* __restrict__ Wo,
    __hip_bfloat16* __restrict__ hpb, __hip_bfloat16* __restrict__ hab,
    __hip_bfloat16* __restrict__ WqT, __hip_bfloat16* __restrict__ WkT,
    __hip_bfloat16* __restrict__ WvT, __hip_bfloat16* __restrict__ WoT) {
    const int b = blockIdx.x, tid = threadIdx.x;
    if (b < 768) {
        const bool isP = (b < 512);
        const float* __restrict__ src = isP ? hp : ha;
        __hip_bfloat16* __restrict__ dst = isP ? hpb : hab;
        const int e8 = ((isP ? b : b - 512) * 256 + tid);  // index of 8-elem chunk
        const float4* s4 = (const float4*)src;
        const float4 lo = s4[e8 * 2 + 0];
        const float4 hi = s4[e8 * 2 + 1];
        __hip_bfloat16 t[8];
        t[0] = __float2bfloat16(lo.x); t[1] = __float2bfloat16(lo.y);
        t[2] = __float2bfloat16(lo.z); t[3] = __float2bfloat16(lo.w);
        t[4] = __float2bfloat16(hi.x); t[5] = __float2bfloat16(hi.y);
        t[6] = __float2bfloat16(hi.z); t[7] = __float2bfloat16(hi.w);
        *(uint4*)(dst + (size_t)e8 * 8) = *(const uint4*)t;
        return;
    }
    // transpose: 4 mats x 64 tiles of 32x32
    __shared__ float tile[32][33];
    const int t = b - 768;
    const int matId = t >> 6, tileId = t & 63;
    const int tr = (tileId >> 3) * 32, tc = (tileId & 7) * 32;
    const float* __restrict__ Ws = (matId == 0) ? Wq : (matId == 1) ? Wk : (matId == 2) ? Wv : Wo;
    __hip_bfloat16* __restrict__ Wd = (matId == 0) ? WqT : (matId == 1) ? WkT : (matId == 2) ? WvT : WoT;

    const int r = tid >> 3, cq = (tid & 7) * 4;
    const float4 in = *(const float4*)&Ws[(size_t)(tr + r) * HIDDEN + tc + cq];
    tile[r][cq + 0] = in.x; tile[r][cq + 1] = in.y;
    tile[r][cq + 2] = in.z; tile[r][cq + 3] = in.w;
    __syncthreads();
    __hip_bfloat16 o[4];
    o[0] = __float2bfloat16(tile[cq + 0][r]);
    o[1] = __float2bfloat16(tile[cq + 1][r]);
    o[2] = __float2bfloat16(tile[cq + 2][r]);
    o[3] = __float2bfloat16(tile[cq + 3][r]);
    *(uint2*)(Wd + (size_t)(tc + r) * HIDDEN + tr + cq) = *(const uint2*)o;
}

// -------------------------------------------------------------------------
// K1: fused QKV MFMA GEMM. blocks [0,256): Q from hpb; [256,384): K+V from hab.
// Block: 16 rows x 256 cols, 4 waves; wave = 16x64 (4 col-frags x 8 k-steps).
// -------------------------------------------------------------------------
__global__ __launch_bounds__(256) void qkv_kernel(
    const __hip_bfloat16* __restrict__ hpb, const __hip_bfloat16* __restrict__ hab,
    const __hip_bfloat16* __restrict__ WqT, const float* __restrict__ bq, float* __restrict__ q_ws,
    const __hip_bfloat16* __restrict__ WkT, const float* __restrict__ bk, float* __restrict__ k_ws,
    const __hip_bfloat16* __restrict__ WvT, const float* __restrict__ bv, float* __restrict__ v_ws) {
    const bool isQ = (blockIdx.x < 256);
    const __hip_bfloat16* __restrict__ A = isQ ? hpb : hab;
    const __hip_bfloat16* __restrict__ W0T = isQ ? WqT : WkT;
    const float* __restrict__ b0 = isQ ? bq : bk;
    float* __restrict__ C0 = isQ ? q_ws : k_ws;
    const int r0 = (isQ ? blockIdx.x : blockIdx.x - 256) * 16;

    const int wave = threadIdx.x >> 6, lane = threadIdx.x & 63;
    const int c0 = wave * 64;
    const int lrow = lane & 15, kgrp = lane >> 4;

    bf16x8 af[8];
    const short* Arow = (const short*)A + (size_t)(r0 + lrow) * HIDDEN + kgrp * 8;
#pragma unroll
    for (int ks = 0; ks < 8; ++ks)
        af[ks] = *(const bf16x8*)(Arow + ks * 32);

    f32x4 acc0[4], acc1[4];
#pragma unroll
    for (int cc = 0; cc < 4; ++cc) {
        acc0[cc] = (f32x4){0.f, 0.f, 0.f, 0.f};
        acc1[cc] = (f32x4){0.f, 0.f, 0.f, 0.f};
    }

#pragma unroll
    for (int cc = 0; cc < 4; ++cc) {
        const short* W0r = (const short*)W0T + (size_t)(c0 + cc * 16 + lrow) * HIDDEN + kgrp * 8;
#pragma unroll
        for (int ks = 0; ks < 8; ++ks)
            acc0[cc] = __builtin_amdgcn_mfma_f32_16x16x32_bf16(
                af[ks], *(const bf16x8*)(W0r + ks * 32), acc0[cc], 0, 0, 0);
        if (!isQ) {
            const short* W1r = (const short*)WvT + (size_t)(c0 + cc * 16 + lrow) * HIDDEN + kgrp * 8;
#pragma unroll
            for (int ks = 0; ks < 8; ++ks)
                acc1[cc] = __builtin_amdgcn_mfma_f32_16x16x32_bf16(
                    af[ks], *(const bf16x8*)(W1r + ks * 32), acc1[cc], 0, 0, 0);
        }
    }

    // D layout: col = lane&15, row = (lane>>4)*4 + reg
    const int colb = lane & 15;
    const int rowb = (lane >> 4) * 4;
#pragma unroll
    for (int cc = 0; cc < 4; ++cc) {
        const int cgl = c0 + cc * 16 + colb;
        const float bias0 = b0[cgl];
#pragma unroll
        for (int rg = 0; rg < 4; ++rg)
            C0[(size_t)(r0 + rowb + rg) * HIDDEN + cgl] = acc0[cc][rg] + bias0;
        if (!isQ) {
            const float bias1 = bv[cgl];
#pragma unroll
            for (int rg = 0; rg < 4; ++rg)
                v_ws[(size_t)(r0 + rowb + rg) * HIDDEN + cgl] = acc1[cc][rg] + bias1;
        }
    }
}

// -------------------------------------------------------------------------
// K2: attn3 — one wave per TWO points (same molecule), all 8 heads.
// RBF/bias computed once per (point,atom). PV: lane owns 4 output cols,
// fully-coalesced V loads shared by both points.
// -------------------------------------------------------------------------
__global__ __launch_bounds__(256) void attn3_kernel(
    const float* __restrict__ q, const float* __restrict__ kmat,
    const float* __restrict__ vmat,
    const float* __restrict__ pos_point, const float* __restrict__ pos_atom,
    const float* __restrict__ W_rbf, const float* __restrict__ b_rbf,
    const float* __restrict__ centers,
    const int* __restrict__ point_batch, const int* __restrict__ atom_batch,
    __hip_bfloat16* __restrict__ aggb) {
    __shared__ float q_lds[8][HIDDEN];          // 8 points/block
    __shared__ float wrbf_lds[NUM_RBF][HEADS];  // 1KB
    __shared__ float cent_lds[NUM_RBF];
    __shared__ float brbf_lds[HEADS];
    __shared__ float w_lds[4][2][HEADS][72];    // [wave][pt][head][atom], pad 72

    const int tid = threadIdx.x, wave = tid >> 6, lane = tid & 63;
    const int j0 = blockIdx.x * 8;

    {   // stage q rows (8 x 256 floats) + constants
        const float4* s4 = (const float4*)(q + (size_t)j0 * HIDDEN);
        float4* d4 = (float4*)&q_lds[0][0];
        d4[tid] = s4[tid];
        d4[tid + 256] = s4[tid + 256];
    }
    if (tid < NUM_RBF * HEADS) ((float*)wrbf_lds)[tid] = W_rbf[tid];
    if (tid < NUM_RBF) cent_lds[tid] = centers[tid];
    if (tid < HEADS) brbf_lds[tid] = b_rbf[tid];
    __syncthreads();

    const int jA = j0 + wave * 2, jB = jA + 1;
    const int m = point_batch[jA];
    const int n = m * ATOMS_PER_MOL + lane;
    const bool valid = (atom_batch[n] == m);

    const float ax = pos_atom[n * 3 + 0], ay = pos_atom[n * 3 + 1], az = pos_atom[n * 3 + 2];
    const float dxA = pos_point[jA * 3 + 0] - ax;
    const float dyA = pos_point[jA * 3 + 1] - ay;
    const float dzA = pos_point[jA * 3 + 2] - az;
    const float dxB = pos_point[jB * 3 + 0] - ax;
    const float dyB = pos_point[jB * 3 + 1] - ay;
    const float dzB = pos_point[jB * 3 + 2] - az;
    const float distA = sqrtf(fmaxf(dxA * dxA + dyA * dyA + dzA * dzA, 0.0f));
    const float distB = sqrtf(fmaxf(dxB * dxB + dyB * dyB + dzB * dzB, 0.0f));

    // bias[h] for both points, RBF once per (point,atom). -1/width = -16
    float biasA[HEADS], biasB[HEADS];
#pragma unroll
    for (int h = 0; h < HEADS; ++h) { biasA[h] = brbf_lds[h]; biasB[h] = brbf_lds[h]; }
#pragma unroll
    for (int r = 0; r < NUM_RBF; ++r) {
        const float c = cent_lds[r];
        const float ddA = distA - c, ddB = distB - c;
        const float eA = __expf(-16.0f * ddA * ddA);
        const float eB = __expf(-16.0f * ddB * ddB);
#pragma unroll
        for (int h = 0; h < HEADS; ++h) {
            const float wr = wrbf_lds[r][h];
            biasA[h] += eA * wr;
            biasB[h] += eB * wr;
        }
    }

    const float scale = 0.17677669529663687f;  // 32^-0.5
    const float* krow = kmat + (size_t)n * HIDDEN;

#pragma unroll
    for (int h = 0; h < HEADS; ++h) {
        const float4* k4 = (const float4*)(krow + h * HEAD_DIM);
        const float4* qA4 = (const float4*)(&q_lds[wave * 2 + 0][h * HEAD_DIM]);
        const float4* qB4 = (const float4*)(&q_lds[wave * 2 + 1][h * HEAD_DIM]);
        float dotA = 0.f, dotB = 0.f;
#pragma unroll
        for (int i = 0; i < HEAD_DIM / 4; ++i) {
            const float4 kv = k4[i];
            const float4 qa = qA4[i];
            const float4 qb = qB4[i];
            dotA += kv.x * qa.x + kv.y * qa.y + kv.z * qa.z + kv.w * qa.w;
            dotB += kv.x * qb.x + kv.y * qb.y + kv.z * qb.z + kv.w * qb.w;
        }
        float sA = valid ? (dotA * scale + biasA[h]) : -1e30f;
        float sB = valid ? (dotB * scale + biasB[h]) : -1e30f;

        float mA = sA, mB = sB;
#pragma unroll
        for (int off = 32; off > 0; off >>= 1) {
            mA = fmaxf(mA, __shfl_xor(mA, off));
            mB = fmaxf(mB, __shfl_xor(mB, off));
        }
        const float eA = __expf(sA - mA);
        const float eB = __expf(sB - mB);
        float ssA = eA, ssB = eB;
#pragma unroll
        for (int off = 32; off > 0; off >>= 1) {
            ssA += __shfl_xor(ssA, off);
            ssB += __shfl_xor(ssB, off);
        }
        w_lds[wave][0][h][lane] = eA / ssA;
        w_lds[wave][1][h][lane] = eB / ssB;
    }

    // PV: lane owns cols [4*lane, 4*lane+3]; head = lane>>3.
    const int c4 = lane * 4;
    const int hh = lane >> 3;
    const float* wA = &w_lds[wave][0][hh][0];
    const float* wB = &w_lds[wave][1][hh][0];
    const float* vbase = vmat + (size_t)(m * ATOMS_PER_MOL) * HIDDEN + c4;
    float4 accA = {0.f, 0.f, 0.f, 0.f};
    float4 accB = {0.f, 0.f, 0.f, 0.f};
#pragma unroll
    for (int a4 = 0; a4 < ATOMS_PER_MOL / 4; ++a4) {
        const float4 wa = *(const float4*)&wA[a4 * 4];
        const float4 wb = *(const float4*)&wB[a4 * 4];
        const float4 v0 = *(const float4*)(vbase + (size_t)(a4 * 4 + 0) * HIDDEN);
        const float4 v1 = *(const float4*)(vbase + (size_t)(a4 * 4 + 1) * HIDDEN);
        const float4 v2 = *(const float4*)(vbase + (size_t)(a4 * 4 + 2) * HIDDEN);
        const float4 v3 = *(const float4*)(vbase + (size_t)(a4 * 4 + 3) * HIDDEN);
        accA.x += wa.x * v0.x + wa.y * v1.x + wa.z * v2.x + wa.w * v3.x;
        accA.y += wa.x * v0.y + wa.y * v1.y + wa.z * v2.y + wa.w * v3.y;
        accA.z += wa.x * v0.z + wa.y * v1.z + wa.z * v2.z + wa.w * v3.z;
        accA.w += wa.x * v0.w + wa.y * v1.w + wa.z * v2.w + wa.w * v3.w;
        accB.x += wb.x * v0.x + wb.y * v1.x + wb.z * v2.x + wb.w * v3.x;
        accB.y += wb.x * v0.y + wb.y * v1.y + wb.z * v2.y + wb.w * v3.y;
        accB.z += wb.x * v0.z + wb.y * v1.z + wb.z * v2.z + wb.w * v3.z;
        accB.w += wb.x * v0.w + wb.y * v1.w + wb.z * v2.w + wb.w * v3.w;
    }
    {
        __hip_bfloat16 oA[4], oB[4];
        oA[0] = __float2bfloat16(accA.x); oA[1] = __float2bfloat16(accA.y);
        oA[2] = __float2bfloat16(accA.z); oA[3] = __float2bfloat16(accA.w);
        oB[0] = __float2bfloat16(accB.x); oB[1] = __float2bfloat16(accB.y);
        oB[2] = __float2bfloat16(accB.z); oB[3] = __float2bfloat16(accB.w);
        *(uint2*)(aggb + (size_t)jA * HIDDEN + c4) = *(const uint2*)oA;
        *(uint2*)(aggb + (size_t)jB * HIDDEN + c4) = *(const uint2*)oB;
    }
}

// -------------------------------------------------------------------------
// K3: out-projection (MFMA) + residual + layernorm fused.
// -------------------------------------------------------------------------
__global__ __launch_bounds__(256) void gemm_o_ln_kernel(
    const __hip_bfloat16* __restrict__ A,
    const __hip_bfloat16* __restrict__ WoT, const float* __restrict__ bo,
    const float* __restrict__ h_point,
    const float* __restrict__ gamma, const float* __restrict__ beta,
    float* __restrict__ out) {
    __shared__ float x_lds[16][HIDDEN + 1];
    __shared__ float red_s[16][4];
    __shared__ float red_q[16][4];

    const int r0 = blockIdx.x * 16;
    const int wave = threadIdx.x >> 6, lane = threadIdx.x & 63;
    const int c0 = wave * 64;
    const int lrow = lane & 15, kgrp = lane >> 4;

    bf16x8 af[8];
    const short* Arow = (const short*)A + (size_t)(r0 + lrow) * HIDDEN + kgrp * 8;
#pragma unroll
    for (int ks = 0; ks < 8; ++ks)
        af[ks] = *(const bf16x8*)(Arow + ks * 32);

    f32x4 acc[4];
#pragma unroll
    for (int cc = 0; cc < 4; ++cc) acc[cc] = (f32x4){0.f, 0.f, 0.f, 0.f};

#pragma unroll
    for (int cc = 0; cc < 4; ++cc) {
        const short* Wr = (const short*)WoT + (size_t)(c0 + cc * 16 + lrow) * HIDDEN + kgrp * 8;
#pragma unroll
        for (int ks = 0; ks < 8; ++ks)
            acc[cc] = __builtin_amdgcn_mfma_f32_16x16x32_bf16(
                af[ks], *(const bf16x8*)(Wr + ks * 32), acc[cc], 0, 0, 0);
    }

    const int colb = lane & 15;
    const int rowb = (lane >> 4) * 4;
#pragma unroll
    for (int cc = 0; cc < 4; ++cc) {
        const int cgl = c0 + cc * 16 + colb;
        const float bias = bo[cgl];
#pragma unroll
        for (int rg = 0; rg < 4; ++rg) {
            const int rl = rowb + rg;
            x_lds[rl][cgl] = acc[cc][rg] + bias + h_point[(size_t)(r0 + rl) * HIDDEN + cgl];
        }
    }
    __syncthreads();

    const int c = threadIdx.x;
    const int ln = c & 63, wv = c >> 6;
    float xv[16];
#pragma unroll
    for (int r = 0; r < 16; ++r) {
        xv[r] = x_lds[r][c];
        float s = xv[r], qq = xv[r] * xv[r];
#pragma unroll
        for (int off = 32; off > 0; off >>= 1) {
            s += __shfl_xor(s, off);
            qq += __shfl_xor(qq, off);
        }
        if (ln == 0) { red_s[r][wv] = s; red_q[r][wv] = qq; }
    }
    __syncthreads();

    const float gc = gamma[c], bc = beta[c];
#pragma unroll
    for (int r = 0; r < 16; ++r) {
        const float mean = (red_s[r][0] + red_s[r][1] + red_s[r][2] + red_s[r][3]) * (1.0f / HIDDEN);
        const float ex2  = (red_q[r][0] + red_q[r][1] + red_q[r][2] + red_q[r][3]) * (1.0f / HIDDEN);
        const float var = ex2 - mean * mean;
        out[(size_t)(r0 + r) * HIDDEN + c] = (xv[r] - mean) * rsqrtf(var + 1e-5f) * gc + bc;
    }
}

// -------------------------------------------------------------------------
extern "C" void kernel_launch(void* const* d_in, const int* in_sizes, int n_in,
                              void* d_out, int out_size, void* d_ws, size_t ws_size,
                              hipStream_t stream) {
    const float* h_point   = (const float*)d_in[0];
    const float* h_atom    = (const float*)d_in[1];
    const float* pos_point = (const float*)d_in[2];
    const float* pos_atom  = (const float*)d_in[3];
    const float* Wq        = (const float*)d_in[4];
    const float* bq        = (const float*)d_in[5];
    const float* Wk        = (const float*)d_in[6];
    const float* bk        = (const float*)d_in[7];
    const float* Wv        = (const float*)d_in[8];
    const float* bv        = (const float*)d_in[9];
    const float* Wo        = (const float*)d_in[10];
    const float* bo        = (const float*)d_in[11];
    const float* W_rbf     = (const float*)d_in[12];
    const float* b_rbf     = (const float*)d_in[13];
    const float* centers   = (const float*)d_in[14];
    const float* gamma     = (const float*)d_in[15];
    const float* beta      = (const float*)d_in[16];
    const int*   point_batch = (const int*)d_in[17];
    const int*   atom_batch  = (const int*)d_in[18];
    float* out = (float*)d_out;

    float* q_ws = (float*)d_ws;                                   // 1048576 f
    float* k_ws = q_ws + (size_t)K_PTS * HIDDEN;                  //  524288 f
    float* v_ws = k_ws + (size_t)N_ATOMS * HIDDEN;                //  524288 f
    __hip_bfloat16* hp_b = (__hip_bfloat16*)(v_ws + (size_t)N_ATOMS * HIDDEN);
    __hip_bfloat16* ha_b = hp_b + (size_t)K_PTS * HIDDEN;
    __hip_bfloat16* WqT = ha_b + (size_t)N_ATOMS * HIDDEN;
    __hip_bfloat16* WkT = WqT + HIDDEN * HIDDEN;
    __hip_bfloat16* WvT = WkT + HIDDEN * HIDDEN;
    __hip_bfloat16* WoT = WvT + HIDDEN * HIDDEN;
    __hip_bfloat16* agg_b = hp_b;   // alias: hp_b dead after qkv

    prep2_kernel<<<1024, 256, 0, stream>>>(h_point, h_atom, Wq, Wk, Wv, Wo,
                                           hp_b, ha_b, WqT, WkT, WvT, WoT);

    qkv_kernel<<<384, 256, 0, stream>>>(hp_b, ha_b,
                                        WqT, bq, q_ws,
                                        WkT, bk, k_ws,
                                        WvT, bv, v_ws);

    attn3_kernel<<<K_PTS / 8, 256, 0, stream>>>(q_ws, k_ws, v_ws, pos_point, pos_atom,
                                                W_rbf, b_rbf, centers,
                                                point_batch, atom_batch, agg_b);

    gemm_o_ln_kernel<<<K_PTS / 16, 256, 0, stream>>>(agg_b, WoT, bo, h_point,
                                                     gamma, beta, out);
}

// Round 5
// 146.744 us; speedup vs baseline: 1.9752x; 1.0022x over previous
//
#include <hip/hip_runtime.h>
#include <hip/hip_bf16.h>

#define HIDDEN 256
#define HEADS 8
#define HEAD_DIM 32
#define NUM_RBF 32
#define K_PTS 4096
#define N_ATOMS 2048
#define B_MOL 32
#define ATOMS_PER_MOL (N_ATOMS / B_MOL)   // 64

typedef __attribute__((ext_vector_type(8))) short bf16x8;
typedef __attribute__((ext_vector_type(4))) float f32x4;

// -------------------------------------------------------------------------
// K0: prepW — weight transposes only (4 mats x 64 tiles of 32x32).
//   WT[c][d] = bf16(W[d][c])
// -------------------------------------------------------------------------
__global__ __launch_bounds__(256) void prepW_kernel(
    const float* __restrict__ Wq, const float* __restrict__ Wk,
    const float* __restrict__ Wv, const float* __restrict__ Wo,
    __hip_bfloat16* __restrict__ WqT, __hip_bfloat16* __restrict__ WkT,
    __hip_bfloat16* __restrict__ WvT, __hip_bfloat16* __restrict__ WoT) {
    __shared__ float tile[32][33];
    const int t = blockIdx.x, tid = threadIdx.x;
    const int matId = t >> 6, tileId = t & 63;
    const int tr = (tileId >> 3) * 32, tc = (tileId & 7) * 32;
    const float* __restrict__ Ws = (matId == 0) ? Wq : (matId == 1) ? Wk : (matId == 2) ? Wv : Wo;
    __hip_bfloat16* __restrict__ Wd = (matId == 0) ? WqT : (matId == 1) ? WkT : (matId == 2) ? WvT : WoT;

    const int r = tid >> 3, cq = (tid & 7) * 4;
    const float4 in = *(const float4*)&Ws[(size_t)(tr + r) * HIDDEN + tc + cq];
    tile[r][cq + 0] = in.x; tile[r][cq + 1] = in.y;
    tile[r][cq + 2] = in.z; tile[r][cq + 3] = in.w;
    __syncthreads();
    __hip_bfloat16 o[4];
    o[0] = __float2bfloat16(tile[cq + 0][r]);
    o[1] = __float2bfloat16(tile[cq + 1][r]);
    o[2] = __float2bfloat16(tile[cq + 2][r]);
    o[3] = __float2bfloat16(tile[cq + 3][r]);
    *(uint2*)(Wd + (size_t)(tc + r) * HIDDEN + tr + cq) = *(const uint2*)o;
}

// -------------------------------------------------------------------------
// K1: fused QKV MFMA GEMM, f32 inputs converted to bf16 fragments on load.
// blocks [0,256): Q from h_point; [256,384): K+V from h_atom.
// Block: 16 rows x 256 cols, 4 waves.
// -------------------------------------------------------------------------
__device__ __forceinline__ bf16x8 cvt8(const float* p) {
    const float4 lo = *(const float4*)p;
    const float4 hi = *(const float4*)(p + 4);
    __hip_bfloat16 t[8];
    t[0] = __float2bfloat16(lo.x); t[1] = __float2bfloat16(lo.y);
    t[2] = __float2bfloat16(lo.z); t[3] = __float2bfloat16(lo.w);
    t[4] = __float2bfloat16(hi.x); t[5] = __float2bfloat16(hi.y);
    t[6] = __float2bfloat16(hi.z); t[7] = __float2bfloat16(hi.w);
    return *(const bf16x8*)t;
}

__global__ __launch_bounds__(256) void qkv2_kernel(
    const float* __restrict__ hp, const float* __restrict__ ha,
    const __hip_bfloat16* __restrict__ WqT, const float* __restrict__ bq, float* __restrict__ q_ws,
    const __hip_bfloat16* __restrict__ WkT, const float* __restrict__ bk, float* __restrict__ k_ws,
    const __hip_bfloat16* __restrict__ WvT, const float* __restrict__ bv, float* __restrict__ v_ws) {
    const bool isQ = (blockIdx.x < 256);
    const float* __restrict__ A = isQ ? hp : ha;
    const __hip_bfloat16* __restrict__ W0T = isQ ? WqT : WkT;
    const float* __restrict__ b0 = isQ ? bq : bk;
    float* __restrict__ C0 = isQ ? q_ws : k_ws;
    const int r0 = (isQ ? blockIdx.x : blockIdx.x - 256) * 16;

    const int wave = threadIdx.x >> 6, lane = threadIdx.x & 63;
    const int c0 = wave * 64;
    const int lrow = lane & 15, kgrp = lane >> 4;

    bf16x8 af[8];
    const float* Arow = A + (size_t)(r0 + lrow) * HIDDEN + kgrp * 8;
#pragma unroll
    for (int ks = 0; ks < 8; ++ks)
        af[ks] = cvt8(Arow + ks * 32);

    f32x4 acc0[4], acc1[4];
#pragma unroll
    for (int cc = 0; cc < 4; ++cc) {
        acc0[cc] = (f32x4){0.f, 0.f, 0.f, 0.f};
        acc1[cc] = (f32x4){0.f, 0.f, 0.f, 0.f};
    }

#pragma unroll
    for (int cc = 0; cc < 4; ++cc) {
        const short* W0r = (const short*)W0T + (size_t)(c0 + cc * 16 + lrow) * HIDDEN + kgrp * 8;
#pragma unroll
        for (int ks = 0; ks < 8; ++ks)
            acc0[cc] = __builtin_amdgcn_mfma_f32_16x16x32_bf16(
                af[ks], *(const bf16x8*)(W0r + ks * 32), acc0[cc], 0, 0, 0);
        if (!isQ) {
            const short* W1r = (const short*)WvT + (size_t)(c0 + cc * 16 + lrow) * HIDDEN + kgrp * 8;
#pragma unroll
            for (int ks = 0; ks < 8; ++ks)
                acc1[cc] = __builtin_amdgcn_mfma_f32_16x16x32_bf16(
                    af[ks], *(const bf16x8*)(W1r + ks * 32), acc1[cc], 0, 0, 0);
        }
    }

    // D layout: col = lane&15, row = (lane>>4)*4 + reg
    const int colb = lane & 15;
    const int rowb = (lane >> 4) * 4;
#pragma unroll
    for (int cc = 0; cc < 4; ++cc) {
        const int cgl = c0 + cc * 16 + colb;
        const float bias0 = b0[cgl];
#pragma unroll
        for (int rg = 0; rg < 4; ++rg)
            C0[(size_t)(r0 + rowb + rg) * HIDDEN + cgl] = acc0[cc][rg] + bias0;
        if (!isQ) {
            const float bias1 = bv[cgl];
#pragma unroll
            for (int rg = 0; rg < 4; ++rg)
                v_ws[(size_t)(r0 + rowb + rg) * HIDDEN + cgl] = acc1[cc][rg] + bias1;
        }
    }
}

// -------------------------------------------------------------------------
// K2: attn_oln — attention (one wave per 2 points, all 8 heads) fused with
// out-projection MFMA (8-row tile via LDS) + residual + layernorm.
// -------------------------------------------------------------------------
#define AGG_PAD (HIDDEN + 16)   // bf16 row stride: 544 B -> 2-way bank alias (free)
#define X_PAD (HIDDEN + 4)

__global__ __launch_bounds__(256) void attn_oln_kernel(
    const float* __restrict__ q, const float* __restrict__ kmat,
    const float* __restrict__ vmat,
    const float* __restrict__ pos_point, const float* __restrict__ pos_atom,
    const float* __restrict__ W_rbf, const float* __restrict__ b_rbf,
    const float* __restrict__ centers,
    const int* __restrict__ point_batch, const int* __restrict__ atom_batch,
    const __hip_bfloat16* __restrict__ WoT, const float* __restrict__ bo,
    const float* __restrict__ h_point,
    const float* __restrict__ gamma, const float* __restrict__ beta,
    float* __restrict__ out) {
    __shared__ float q_lds[8][HIDDEN];            // 8 KB
    __shared__ float wrbf_lds[NUM_RBF][HEADS];    // 1 KB
    __shared__ float cent_lds[NUM_RBF];
    __shared__ float brbf_lds[HEADS];
    __shared__ float w_lds[4][2][HEADS][72];      // 18.4 KB
    __shared__ __hip_bfloat16 agg_lds[8][AGG_PAD]; // 4.3 KB
    __shared__ float x_lds[8][X_PAD];             // 8.1 KB
    __shared__ float red_s[8][4];
    __shared__ float red_q[8][4];

    const int tid = threadIdx.x, wave = tid >> 6, lane = tid & 63;
    const int j0 = blockIdx.x * 8;

    {   // stage q rows (8 x 256 floats) + constants
        const float4* s4 = (const float4*)(q + (size_t)j0 * HIDDEN);
        float4* d4 = (float4*)&q_lds[0][0];
        d4[tid] = s4[tid];
        d4[tid + 256] = s4[tid + 256];
    }
    if (tid < NUM_RBF * HEADS) ((float*)wrbf_lds)[tid] = W_rbf[tid];
    if (tid < NUM_RBF) cent_lds[tid] = centers[tid];
    if (tid < HEADS) brbf_lds[tid] = b_rbf[tid];
    __syncthreads();

    const int jA = j0 + wave * 2, jB = jA + 1;
    const int m = point_batch[jA];
    const int n = m * ATOMS_PER_MOL + lane;
    const bool valid = (atom_batch[n] == m);

    const float ax = pos_atom[n * 3 + 0], ay = pos_atom[n * 3 + 1], az = pos_atom[n * 3 + 2];
    const float dxA = pos_point[jA * 3 + 0] - ax;
    const float dyA = pos_point[jA * 3 + 1] - ay;
    const float dzA = pos_point[jA * 3 + 2] - az;
    const float dxB = pos_point[jB * 3 + 0] - ax;
    const float dyB = pos_point[jB * 3 + 1] - ay;
    const float dzB = pos_point[jB * 3 + 2] - az;
    const float distA = sqrtf(fmaxf(dxA * dxA + dyA * dyA + dzA * dzA, 0.0f));
    const float distB = sqrtf(fmaxf(dxB * dxB + dyB * dyB + dzB * dzB, 0.0f));

    // bias[h] for both points, RBF once per (point,atom). -1/width = -16
    float biasA[HEADS], biasB[HEADS];
#pragma unroll
    for (int h = 0; h < HEADS; ++h) { biasA[h] = brbf_lds[h]; biasB[h] = brbf_lds[h]; }
#pragma unroll
    for (int r = 0; r < NUM_RBF; ++r) {
        const float c = cent_lds[r];
        const float ddA = distA - c, ddB = distB - c;
        const float eA = __expf(-16.0f * ddA * ddA);
        const float eB = __expf(-16.0f * ddB * ddB);
#pragma unroll
        for (int h = 0; h < HEADS; ++h) {
            const float wr = wrbf_lds[r][h];
            biasA[h] += eA * wr;
            biasB[h] += eB * wr;
        }
    }

    const float scale = 0.17677669529663687f;  // 32^-0.5
    const float* krow = kmat + (size_t)n * HIDDEN;

#pragma unroll
    for (int h = 0; h < HEADS; ++h) {
        const float4* k4 = (const float4*)(krow + h * HEAD_DIM);
        const float4* qA4 = (const float4*)(&q_lds[wave * 2 + 0][h * HEAD_DIM]);
        const float4* qB4 = (const float4*)(&q_lds[wave * 2 + 1][h * HEAD_DIM]);
        float dotA = 0.f, dotB = 0.f;
#pragma unroll
        for (int i = 0; i < HEAD_DIM / 4; ++i) {
            const float4 kv = k4[i];
            const float4 qa = qA4[i];
            const float4 qb = qB4[i];
            dotA += kv.x * qa.x + kv.y * qa.y + kv.z * qa.z + kv.w * qa.w;
            dotB += kv.x * qb.x + kv.y * qb.y + kv.z * qb.z + kv.w * qb.w;
        }
        float sA = valid ? (dotA * scale + biasA[h]) : -1e30f;
        float sB = valid ? (dotB * scale + biasB[h]) : -1e30f;

        float mA = sA, mB = sB;
#pragma unroll
        for (int off = 32; off > 0; off >>= 1) {
            mA = fmaxf(mA, __shfl_xor(mA, off));
            mB = fmaxf(mB, __shfl_xor(mB, off));
        }
        const float eA = __expf(sA - mA);
        const float eB = __expf(sB - mB);
        float ssA = eA, ssB = eB;
#pragma unroll
        for (int off = 32; off > 0; off >>= 1) {
            ssA += __shfl_xor(ssA, off);
            ssB += __shfl_xor(ssB, off);
        }
        w_lds[wave][0][h][lane] = eA / ssA;
        w_lds[wave][1][h][lane] = eB / ssB;
    }

    // PV: lane owns cols [4*lane, 4*lane+3]; head = lane>>3.
    const int c4 = lane * 4;
    const int hh = lane >> 3;
    {
        const float* wA = &w_lds[wave][0][hh][0];
        const float* wB = &w_lds[wave][1][hh][0];
        const float* vbase = vmat + (size_t)(m * ATOMS_PER_MOL) * HIDDEN + c4;
        float4 accA = {0.f, 0.f, 0.f, 0.f};
        float4 accB = {0.f, 0.f, 0.f, 0.f};
#pragma unroll
        for (int a4 = 0; a4 < ATOMS_PER_MOL / 4; ++a4) {
            const float4 wa = *(const float4*)&wA[a4 * 4];
            const float4 wb = *(const float4*)&wB[a4 * 4];
            const float4 v0 = *(const float4*)(vbase + (size_t)(a4 * 4 + 0) * HIDDEN);
            const float4 v1 = *(const float4*)(vbase + (size_t)(a4 * 4 + 1) * HIDDEN);
            const float4 v2 = *(const float4*)(vbase + (size_t)(a4 * 4 + 2) * HIDDEN);
            const float4 v3 = *(const float4*)(vbase + (size_t)(a4 * 4 + 3) * HIDDEN);
            accA.x += wa.x * v0.x + wa.y * v1.x + wa.z * v2.x + wa.w * v3.x;
            accA.y += wa.x * v0.y + wa.y * v1.y + wa.z * v2.y + wa.w * v3.y;
            accA.z += wa.x * v0.z + wa.y * v1.z + wa.z * v2.z + wa.w * v3.z;
            accA.w += wa.x * v0.w + wa.y * v1.w + wa.z * v2.w + wa.w * v3.w;
            accB.x += wb.x * v0.x + wb.y * v1.x + wb.z * v2.x + wb.w * v3.x;
            accB.y += wb.x * v0.y + wb.y * v1.y + wb.z * v2.y + wb.w * v3.y;
            accB.z += wb.x * v0.z + wb.y * v1.z + wb.z * v2.z + wb.w * v3.z;
            accB.w += wb.x * v0.w + wb.y * v1.w + wb.z * v2.w + wb.w * v3.w;
        }
        __hip_bfloat16 oA[4], oB[4];
        oA[0] = __float2bfloat16(accA.x); oA[1] = __float2bfloat16(accA.y);
        oA[2] = __float2bfloat16(accA.z); oA[3] = __float2bfloat16(accA.w);
        oB[0] = __float2bfloat16(accB.x); oB[1] = __float2bfloat16(accB.y);
        oB[2] = __float2bfloat16(accB.z); oB[3] = __float2bfloat16(accB.w);
        *(uint2*)(&agg_lds[wave * 2 + 0][c4]) = *(const uint2*)oA;
        *(uint2*)(&agg_lds[wave * 2 + 1][c4]) = *(const uint2*)oB;
    }
    __syncthreads();

    // ---- out-projection MFMA: 8 valid rows (8-15 zero), 256 cols ----
    const int c0 = wave * 64;
    const int lrow = lane & 15, kgrp = lane >> 4;
    bf16x8 af[8];
    const bf16x8 zf = {0, 0, 0, 0, 0, 0, 0, 0};
#pragma unroll
    for (int ks = 0; ks < 8; ++ks)
        af[ks] = (lrow < 8) ? *(const bf16x8*)(&agg_lds[lrow & 7][kgrp * 8 + ks * 32]) : zf;

    f32x4 acc[4];
#pragma unroll
    for (int cc = 0; cc < 4; ++cc) acc[cc] = (f32x4){0.f, 0.f, 0.f, 0.f};
#pragma unroll
    for (int cc = 0; cc < 4; ++cc) {
        const short* Wr = (const short*)WoT + (size_t)(c0 + cc * 16 + lrow) * HIDDEN + kgrp * 8;
#pragma unroll
        for (int ks = 0; ks < 8; ++ks)
            acc[cc] = __builtin_amdgcn_mfma_f32_16x16x32_bf16(
                af[ks], *(const bf16x8*)(Wr + ks * 32), acc[cc], 0, 0, 0);
    }

    // x = proj + bias + residual for rows 0..7
    const int colb = lane & 15;
    const int rowb = (lane >> 4) * 4;
#pragma unroll
    for (int cc = 0; cc < 4; ++cc) {
        const int cgl = c0 + cc * 16 + colb;
        const float bias = bo[cgl];
#pragma unroll
        for (int rg = 0; rg < 4; ++rg) {
            const int rl = rowb + rg;
            if (rl < 8)
                x_lds[rl][cgl] = acc[cc][rg] + bias + h_point[(size_t)(j0 + rl) * HIDDEN + cgl];
        }
    }
    __syncthreads();

    // ---- layernorm over 8 rows ----
    const int c = tid;
    const int ln = c & 63, wv = c >> 6;
    float xv[8];
#pragma unroll
    for (int r = 0; r < 8; ++r) {
        xv[r] = x_lds[r][c];
        float s = xv[r], qq = xv[r] * xv[r];
#pragma unroll
        for (int off = 32; off > 0; off >>= 1) {
            s += __shfl_xor(s, off);
            qq += __shfl_xor(qq, off);
        }
        if (ln == 0) { red_s[r][wv] = s; red_q[r][wv] = qq; }
    }
    __syncthreads();

    const float gc = gamma[c], bc = beta[c];
#pragma unroll
    for (int r = 0; r < 8; ++r) {
        const float mean = (red_s[r][0] + red_s[r][1] + red_s[r][2] + red_s[r][3]) * (1.0f / HIDDEN);
        const float ex2  = (red_q[r][0] + red_q[r][1] + red_q[r][2] + red_q[r][3]) * (1.0f / HIDDEN);
        const float var = ex2 - mean * mean;
        out[(size_t)(j0 + r) * HIDDEN + c] = (xv[r] - mean) * rsqrtf(var + 1e-5f) * gc + bc;
    }
}

// -------------------------------------------------------------------------
extern "C" void kernel_launch(void* const* d_in, const int* in_sizes, int n_in,
                              void* d_out, int out_size, void* d_ws, size_t ws_size,
                              hipStream_t stream) {
    const float* h_point   = (const float*)d_in[0];
    const float* h_atom    = (const float*)d_in[1];
    const float* pos_point = (const float*)d_in[2];
    const float* pos_atom  = (const float*)d_in[3];
    const float* Wq        = (const float*)d_in[4];
    const float* bq        = (const float*)d_in[5];
    const float* Wk        = (const float*)d_in[6];
    const float* bk        = (const float*)d_in[7];
    const float* Wv        = (const float*)d_in[8];
    const float* bv        = (const float*)d_in[9];
    const float* Wo        = (const float*)d_in[10];
    const float* bo        = (const float*)d_in[11];
    const float* W_rbf     = (const float*)d_in[12];
    const float* b_rbf     = (const float*)d_in[13];
    const float* centers   = (const float*)d_in[14];
    const float* gamma     = (const float*)d_in[15];
    const float* beta      = (const float*)d_in[16];
    const int*   point_batch = (const int*)d_in[17];
    const int*   atom_batch  = (const int*)d_in[18];
    float* out = (float*)d_out;

    float* q_ws = (float*)d_ws;                                   // 1048576 f
    float* k_ws = q_ws + (size_t)K_PTS * HIDDEN;                  //  524288 f
    float* v_ws = k_ws + (size_t)N_ATOMS * HIDDEN;                //  524288 f
    __hip_bfloat16* WqT = (__hip_bfloat16*)(v_ws + (size_t)N_ATOMS * HIDDEN);
    __hip_bfloat16* WkT = WqT + HIDDEN * HIDDEN;
    __hip_bfloat16* WvT = WkT + HIDDEN * HIDDEN;
    __hip_bfloat16* WoT = WvT + HIDDEN * HIDDEN;

    prepW_kernel<<<256, 256, 0, stream>>>(Wq, Wk, Wv, Wo, WqT, WkT, WvT, WoT);

    qkv2_kernel<<<384, 256, 0, stream>>>(h_point, h_atom,
                                         WqT, bq, q_ws,
                                         WkT, bk, k_ws,
                                         WvT, bv, v_ws);

    attn_oln_kernel<<<K_PTS / 8, 256, 0, stream>>>(q_ws, k_ws, v_ws,
                                                   pos_point, pos_atom,
                                                   W_rbf, b_rbf, centers,
                                                   point_batch, atom_batch,
                                                   WoT, bo, h_point, gamma, beta,
                                                   out);
}